// Round 7
// baseline (145.882 us; speedup 1.0000x reference)
//
#include <hip/hip_runtime.h>
#include <hip/hip_bf16.h>
#include <cmath>

using f32x4 = __attribute__((ext_vector_type(4))) float;
using s16x8 = __attribute__((ext_vector_type(8))) short;
using u16x4 = __attribute__((ext_vector_type(4))) unsigned short;

__device__ __forceinline__ float bf2f(unsigned short u){
  union { unsigned int i; float f; } v; v.i = ((unsigned int)u) << 16; return v.f;
}
__device__ __forceinline__ unsigned short f2bf(float f){
  union { float f; unsigned int i; } v; v.f = f;
  return (unsigned short)((v.i + 0x7FFFu + ((v.i >> 16) & 1u)) >> 16);
}

#define GLDS16(g, l) __builtin_amdgcn_global_load_lds( \
    (const __attribute__((address_space(1))) unsigned int*)(g), \
    (__attribute__((address_space(3))) unsigned int*)(l), 16, 0, 0)

// ---------------- prep: convert all small operands to bf16 ----------------
__global__ void k_prep(const float* __restrict__ Wd, const float* __restrict__ Wu,
                       const float* __restrict__ Wt, const float* __restrict__ Wf,
                       const float* __restrict__ Ap, const float* __restrict__ Bp,
                       const int* __restrict__ layerp,
                       unsigned short* __restrict__ Wdb, unsigned short* __restrict__ Wub,
                       unsigned short* __restrict__ Wtb, unsigned short* __restrict__ WB,
                       unsigned short* __restrict__ Ab, unsigned short* __restrict__ Blb){
  int idx = blockIdx.x * 256 + threadIdx.x;
  switch (blockIdx.y){
    case 0: if (idx < 24576)  Wdb[idx] = f2bf(Wd[idx]); break;
    case 1: if (idx < 73728)  Wub[idx] = f2bf(Wu[idx]); break;
    case 2: if (idx < 589824) Wtb[idx] = f2bf(Wt[idx]); break;
    case 3: if (idx < 688128){
      int n = idx / 896, c = idx - n * 896;
      WB[idx] = (c < 768) ? f2bf(Wf[n * 768 + c]) : (unsigned short)0;
    } break;
    case 4: if (idx < 28672){
      int r = idx >> 8;
      Ab[idx] = (r < 100) ? f2bf(Ap[idx]) : (unsigned short)0;
    } break;
    case 5: if (idx < 65536) Blb[idx] = f2bf(Bp[(long)(*layerp) * 65536 + idx]); break;
  }
}

// ---------------- generic 1-wave MFMA mini-GEMM: out = epi(A @ B^T + bias) ----------------
template<int EPI>
__global__ __launch_bounds__(64) void k_mm(const unsigned short* __restrict__ A, int lda,
    const unsigned short* __restrict__ B, int ldb, int K,
    const float* __restrict__ bias, unsigned short* __restrict__ out, int ldo){
  int l = threadIdx.x, l15 = l & 15, lhi = l >> 4;
  int m0 = blockIdx.x * 16, n0 = blockIdx.y * 16;
  f32x4 acc = (f32x4)0.0f;
  #pragma unroll 4
  for (int k0 = 0; k0 < K; k0 += 32){
    s16x8 a = *(const s16x8*)(A + (long)(m0 + l15) * lda + k0 + lhi * 8);
    s16x8 b = *(const s16x8*)(B + (long)(n0 + l15) * ldb + k0 + lhi * 8);
    acc = __builtin_amdgcn_mfma_f32_16x16x32_bf16(a, b, acc, 0, 0, 0);
  }
  int col = n0 + l15;
  float bv = bias ? bias[col] : 0.0f;
  #pragma unroll
  for (int r = 0; r < 4; r++){
    int row = m0 + lhi * 4 + r;
    float v = acc[r] + bv;
    if (EPI == 0){
      v = 0.5f * v * (1.0f + erff(v * 0.70710678118654752f));
      out[(long)row * ldo + col] = f2bf(v);
    } else if (EPI == 1){
      out[(long)col * ldo + row] = f2bf(v);
    } else if (EPI == 2){
      out[(long)row * ldo + col] = f2bf(v);
    } else {
      out[(long)col * 896 + 768 + row] = (row < 100) ? f2bf(v) : (unsigned short)0;
    }
  }
}

// ---------------- fused cvt + logits + softmax, LDS-staged GEMM form ----------------
__global__ __launch_bounds__(256, 4) void k_attn(const float* __restrict__ xf,
    const unsigned short* __restrict__ tokensb, unsigned short* __restrict__ xb,
    unsigned short* __restrict__ Pbuf){
  __shared__ __align__(16) char smem[40960];
  unsigned short* Xs = (unsigned short*)smem;            // [32][128] us, swizzled
  unsigned short* Ts = (unsigned short*)(smem + 8192);   // [112][128] us, swizzled
  float* st = (float*)smem;                              // post-loop stash overlay

  int tid = threadIdx.x, w = tid >> 6, l = tid & 63;
  int l15 = l & 15, lhi = l >> 4;
  int rg = w >> 1, kh = w & 1;
  long R0 = (long)blockIdx.x * 32;

  f32x4 acc[7];
  #pragma unroll
  for (int nf = 0; nf < 7; nf++) acc[nf] = (f32x4)0.0f;

  int xrow = tid >> 5;           // 0..7 (8 rows per round)
  int xcol = (tid & 31) * 4;     // f32 col within 128-chunk (coalesced)

  for (int it = 0; it < 6; it++){
    #pragma unroll
    for (int i = 0; i < 7; i++){
      int g = (w * 7 + i) * 4 + (l >> 4);          // token row 0..111
      const unsigned short* src = tokensb + (long)g * 768 + it * 128
                                + (((l & 15) * 8) ^ ((g & 7) << 3));
      GLDS16(src, Ts + (w * 7 + i) * 512);
    }
    #pragma unroll
    for (int rnd = 0; rnd < 4; rnd++){
      int row = rnd * 8 + xrow;
      f32x4 v = *(const f32x4*)(xf + (R0 + row) * 768 + it * 128 + xcol);
      u16x4 c;
      #pragma unroll
      for (int j = 0; j < 4; j++) c[j] = f2bf(v[j]);
      *(u16x4*)(xb + (R0 + row) * 768 + it * 128 + xcol) = c;
      *(u16x4*)(Xs + row * 128 + (xcol ^ ((row & 7) << 3))) = c;
    }
    __syncthreads();
    int ar = rg * 16 + l15;
    #pragma unroll
    for (int kk = 0; kk < 2; kk++){
      int coff = kh * 64 + kk * 32 + lhi * 8;
      s16x8 a = *(const s16x8*)(Xs + ar * 128 + (coff ^ ((ar & 7) << 3)));
      #pragma unroll
      for (int nf = 0; nf < 7; nf++){
        int br = nf * 16 + l15;
        s16x8 b = *(const s16x8*)(Ts + br * 128 + (coff ^ ((br & 7) << 3)));
        acc[nf] = __builtin_amdgcn_mfma_f32_16x16x32_bf16(a, b, acc[nf], 0, 0, 0);
      }
    }
    __syncthreads();
  }

  if (kh == 1){
    int widx = rg * 64 + l;
    #pragma unroll
    for (int nf = 0; nf < 7; nf++)
      #pragma unroll
      for (int r = 0; r < 4; r++)
        st[widx * 29 + nf * 4 + r] = acc[nf][r];
  }
  __syncthreads();
  if (kh == 0){
    const float sc = 0.03608439182435161f; // 768^-0.5
    int widx = rg * 64 + l;
    float lg[4][7];
    #pragma unroll
    for (int nf = 0; nf < 7; nf++)
      #pragma unroll
      for (int r = 0; r < 4; r++)
        lg[r][nf] = (acc[nf][r] + st[widx * 29 + nf * 4 + r]) * sc;
    #pragma unroll
    for (int r = 0; r < 4; r++){
      float mx = -1e30f;
      #pragma unroll
      for (int nf = 0; nf < 7; nf++){
        int col = nf * 16 + l15;
        if (col < 100 && lg[r][nf] > mx) mx = lg[r][nf];
      }
      mx = fmaxf(mx, __shfl_xor(mx, 1));
      mx = fmaxf(mx, __shfl_xor(mx, 2));
      mx = fmaxf(mx, __shfl_xor(mx, 4));
      mx = fmaxf(mx, __shfl_xor(mx, 8));
      float p[7], sm = 0.f;
      #pragma unroll
      for (int nf = 0; nf < 7; nf++){
        int col = nf * 16 + l15;
        float v = (col < 100) ? __expf(lg[r][nf] - mx) : 0.f;
        p[nf] = v; sm += v;
      }
      sm += __shfl_xor(sm, 1);
      sm += __shfl_xor(sm, 2);
      sm += __shfl_xor(sm, 4);
      sm += __shfl_xor(sm, 8);
      float inv = 1.f / sm;
      long grow = R0 + rg * 16 + lhi * 4 + r;
      #pragma unroll
      for (int nf = 0; nf < 7; nf++)
        Pbuf[grow * 128 + nf * 16 + l15] = f2bf(p[nf] * inv);
      Pbuf[grow * 128 + 112 + l15] = 0;
    }
  }
}

// ---------------- big GEMM: out = feats + scale*([xb|P] @ WB^T + bf) ----------------
// m201 geometry: BM=BN=256, BK=64, 8 waves (2M x 4N), wave tile 128x64.
// 4 phases per K-tile, dbuf LDS, counted vmcnt(2) once per tile, T2 swizzle,
// T5 setprio, coalesced LDS-staged epilogue.
__global__ __launch_bounds__(512, 2) void k_gemm(const unsigned short* __restrict__ xb,
    const unsigned short* __restrict__ Pbuf, const unsigned short* __restrict__ WB,
    const float* __restrict__ bfv, const float* __restrict__ scalep,
    float* __restrict__ outf){
  extern __shared__ __align__(16) unsigned short lds[];  // A: 2x16384 us, B: 2x16384 us
  int bid = blockIdx.x;                 // 384 = 8 XCD * 48
  int sid = (bid & 7) * 48 + (bid >> 3);
  int mt = sid / 3, nt = sid - mt * 3;
  long brow = (long)mt * 256;
  int bcol = nt * 256;
  int tid = threadIdx.x, w = tid >> 6, l = tid & 63;
  int l15 = l & 15, lhi = l >> 4;
  int wm = w >> 2, wn = w & 3;          // wave tile: rows wm*128.., cols wn*64..
  int lrow = l >> 3;
  int lsw  = ((l & 7) ^ lrow) * 8;      // pre-swizzled source col (T2 both-sides rule)

  f32x4 acc[8][4];
  #pragma unroll
  for (int m = 0; m < 8; m++)
    #pragma unroll
    for (int n = 0; n < 4; n++) acc[m][n] = (f32x4)0.0f;

  // stage pair P (P=0,1: A halves; P=2,3: B halves) of K-tile T into buffer BUF
  #define STAGE_PAIR(BUF, T, P) { \
    _Pragma("unroll") \
    for (int i2 = 0; i2 < 2; i2++){ \
      int ii = ((P) & 1) * 2 + i2; \
      int r = (w * 4 + ii) * 8 + lrow; \
      if ((P) < 2){ \
        const unsigned short* ga = ((T) < 12) \
          ? xb   + (brow + r) * 768 + (T) * 64 + lsw \
          : Pbuf + (brow + r) * 128 + ((T) - 12) * 64 + lsw; \
        GLDS16(ga, lds + (BUF) * 16384 + (w * 4 + ii) * 512); \
      } else { \
        const unsigned short* gb = WB + (long)(bcol + r) * 896 + (T) * 64 + lsw; \
        GLDS16(gb, lds + 32768 + (BUF) * 16384 + (w * 4 + ii) * 512); \
      } \
    } }

  #define LDA(dst, M, KS) { \
    int ar = wm * 128 + (M) * 16 + l15; \
    int xo = ((KS) * 64 + lhi * 16) ^ ((ar & 7) << 4); \
    dst = *(const s16x8*)(Abuf + ar * 64 + (xo >> 1)); }
  #define LDB(dst, N, KS) { \
    int br = wn * 64 + (N) * 16 + l15; \
    int xo = ((KS) * 64 + lhi * 16) ^ ((br & 7) << 4); \
    dst = *(const s16x8*)(Bbuf + br * 64 + (xo >> 1)); }

  // prologue: stage K-tile 0 fully into buf 0
  STAGE_PAIR(0, 0, 0); STAGE_PAIR(0, 0, 1); STAGE_PAIR(0, 0, 2); STAGE_PAIR(0, 0, 3);

  for (int t = 0; t < 14; t++){
    const unsigned short* Abuf = lds + (t & 1) * 16384;
    const unsigned short* Bbuf = lds + 32768 + (t & 1) * 16384;
    int nb = (t & 1) ^ 1;
    s16x8 af[4], bk[4];
    // ---- phase 0: (qm=0, ks=0) ----
    if (t < 13){
      STAGE_PAIR(nb, t + 1, 0);
      asm volatile("s_waitcnt vmcnt(2)" ::: "memory");
    } else {
      asm volatile("s_waitcnt vmcnt(0)" ::: "memory");
    }
    __builtin_amdgcn_s_barrier();
    #pragma unroll
    for (int j = 0; j < 4; j++) LDB(bk[j], j, 0);
    #pragma unroll
    for (int j = 0; j < 4; j++) LDA(af[j], j, 0);
    __builtin_amdgcn_s_setprio(1);
    #pragma unroll
    for (int m = 0; m < 4; m++)
      #pragma unroll
      for (int n = 0; n < 4; n++)
        acc[m][n] = __builtin_amdgcn_mfma_f32_16x16x32_bf16(af[m], bk[n], acc[m][n], 0, 0, 0);
    __builtin_amdgcn_s_setprio(0);
    __builtin_amdgcn_s_barrier();
    // ---- phase 1: (qm=1, ks=0) ----
    if (t < 13) STAGE_PAIR(nb, t + 1, 1);
    #pragma unroll
    for (int j = 0; j < 4; j++) LDA(af[j], 4 + j, 0);
    __builtin_amdgcn_s_setprio(1);
    #pragma unroll
    for (int m = 0; m < 4; m++)
      #pragma unroll
      for (int n = 0; n < 4; n++)
        acc[4 + m][n] = __builtin_amdgcn_mfma_f32_16x16x32_bf16(af[m], bk[n], acc[4 + m][n], 0, 0, 0);
    __builtin_amdgcn_s_setprio(0);
    __builtin_amdgcn_s_barrier();
    // ---- phase 2: (qm=0, ks=1) ----
    if (t < 13) STAGE_PAIR(nb, t + 1, 2);
    #pragma unroll
    for (int j = 0; j < 4; j++) LDB(bk[j], j, 1);
    #pragma unroll
    for (int j = 0; j < 4; j++) LDA(af[j], j, 1);
    __builtin_amdgcn_s_setprio(1);
    #pragma unroll
    for (int m = 0; m < 4; m++)
      #pragma unroll
      for (int n = 0; n < 4; n++)
        acc[m][n] = __builtin_amdgcn_mfma_f32_16x16x32_bf16(af[m], bk[n], acc[m][n], 0, 0, 0);
    __builtin_amdgcn_s_setprio(0);
    __builtin_amdgcn_s_barrier();
    // ---- phase 3: (qm=1, ks=1) ----
    if (t < 13) STAGE_PAIR(nb, t + 1, 3);
    #pragma unroll
    for (int j = 0; j < 4; j++) LDA(af[j], 4 + j, 1);
    __builtin_amdgcn_s_setprio(1);
    #pragma unroll
    for (int m = 0; m < 4; m++)
      #pragma unroll
      for (int n = 0; n < 4; n++)
        acc[4 + m][n] = __builtin_amdgcn_mfma_f32_16x16x32_bf16(af[m], bk[n], acc[4 + m][n], 0, 0, 0);
    __builtin_amdgcn_s_setprio(0);
    __builtin_amdgcn_s_barrier();
  }
  #undef STAGE_PAIR
  #undef LDA
  #undef LDB

  // ---- coalesced epilogue: acc -> LDS (f32, stride 260) -> 256B-coalesced stores ----
  float* stf = (float*)lds;      // 128 x 260 f32 = 133,120 B (dyn LDS = 135,168)
  float scale = *scalep;
  #pragma unroll
  for (int c = 0; c < 2; c++){
    if (wm == c){
      #pragma unroll
      for (int m = 0; m < 8; m++)
        #pragma unroll
        for (int n = 0; n < 4; n++)
          #pragma unroll
          for (int r = 0; r < 4; r++){
            int row = m * 16 + lhi * 4 + r;
            stf[row * 260 + wn * 64 + n * 16 + l15] = acc[m][n][r];
          }
    }
    __syncthreads();
    #pragma unroll
    for (int rp = 0; rp < 4; rp++){
      int row = rp * 32 + (tid >> 4);
      long grow = brow + c * 128 + row;
      #pragma unroll
      for (int cb = 0; cb < 4; cb++){
        int col = cb * 64 + (tid & 15) * 4;
        f32x4 v = *(const f32x4*)(stf + row * 260 + col);
        int gcol = bcol + col;
        f32x4 bias = *(const f32x4*)(bfv + gcol);
        u16x4 fb = *(const u16x4*)(xb + grow * 768 + gcol);
        f32x4 o;
        #pragma unroll
        for (int j = 0; j < 4; j++) o[j] = bf2f(fb[j]) + scale * (v[j] + bias[j]);
        *(f32x4*)(outf + grow * 768 + gcol) = o;
      }
    }
    __syncthreads();
  }
}

extern "C" void kernel_launch(void* const* d_in, const int* in_sizes, int n_in,
                              void* d_out, int out_size, void* d_ws, size_t ws_size,
                              hipStream_t stream) {
  const float* x   = (const float*)d_in[0];
  const float* Wd  = (const float*)d_in[1];
  const float* bd  = (const float*)d_in[2];
  const float* Wu  = (const float*)d_in[3];
  const float* bu  = (const float*)d_in[4];
  const float* Wt  = (const float*)d_in[5];
  const float* bt  = (const float*)d_in[6];
  const float* Wf  = (const float*)d_in[7];
  const float* bfv = (const float*)d_in[8];
  const float* Ap  = (const float*)d_in[9];
  const float* Bp  = (const float*)d_in[10];
  const float* scalep = (const float*)d_in[11];
  const int* layerp   = (const int*)d_in[12];
  float* out = (float*)d_out;

  char* ws = (char*)d_ws;
  unsigned short* xb      = (unsigned short*)(ws);              // 50,331,648
  unsigned short* Pbuf    = (unsigned short*)(ws + 50331648);   //  8,388,608
  unsigned short* WB      = (unsigned short*)(ws + 58720256);   //  1,376,256 (768 x 896)
  unsigned short* Wtb     = (unsigned short*)(ws + 60096512);   //  1,179,648 (768 x 768)
  unsigned short* tokensb = (unsigned short*)(ws + 61276160);   //    172,032 (112 x 768)
  unsigned short* t2fb    = (unsigned short*)(ws + 61448192);   //    172,032 (112 x 768)
  unsigned short* Ab      = (unsigned short*)(ws + 61620224);   //     57,344 (112 x 256)
  unsigned short* Blb     = (unsigned short*)(ws + 61677568);   //    131,072 (256 x 256)
  unsigned short* Wdb     = (unsigned short*)(ws + 61808640);   //     49,152 ( 96 x 256)
  unsigned short* Wub     = (unsigned short*)(ws + 61857792);   //    147,456 (768 x  96)
  unsigned short* hb      = (unsigned short*)(ws + 62005248);   //     49,152 (256 x  96)
  unsigned short* Bfmt    = (unsigned short*)(ws + 62054400);   //    393,216 (768 x 256, Bf^T)

  const float* xf = x + 32 * 768;   // feats (skip cls rows)
  float* outf = out + 32 * 768;

  static int lds_attr_set = 0;
  if (!lds_attr_set){
    hipFuncSetAttribute((const void*)k_gemm, hipFuncAttributeMaxDynamicSharedMemorySize, 135168);
    lds_attr_set = 1;
  }

  // cls passthrough
  hipMemcpyAsync(d_out, d_in[0], 32 * 768 * sizeof(float), hipMemcpyDeviceToDevice, stream);

  k_prep<<<dim3(2688, 6), 256, 0, stream>>>(Wd, Wu, Wt, Wf, Ap, Bp, layerp,
                                            Wdb, Wub, Wtb, WB, Ab, Blb);
  k_mm<0><<<dim3(16, 6),  64, 0, stream>>>(Blb, 256, Wdb, 256, 256, bd, hb, 96);
  k_mm<1><<<dim3(16, 48), 64, 0, stream>>>(hb, 96, Wub, 96, 96, bu, Bfmt, 256);
  k_mm<2><<<dim3(7, 48),  64, 0, stream>>>(Ab, 256, Bfmt, 256, 256, nullptr, tokensb, 768);
  k_mm<2><<<dim3(7, 48),  64, 0, stream>>>(tokensb, 768, Wtb, 768, 768, bt, t2fb, 768);
  k_mm<3><<<dim3(7, 48),  64, 0, stream>>>(t2fb, 768, WB, 896, 768, nullptr, WB, 0);

  k_attn<<<1024, 256, 0, stream>>>(xf, tokensb, xb, Pbuf);
  k_gemm<<<384, 512, 135168, stream>>>(xb, Pbuf, WB, bfv, scalep, outf);
}

// Round 8
// 136.592 us; speedup vs baseline: 1.0680x; 1.0680x over previous
//
#include <hip/hip_runtime.h>
#include <hip/hip_bf16.h>
#include <cmath>

using f32x4 = __attribute__((ext_vector_type(4))) float;
using s16x8 = __attribute__((ext_vector_type(8))) short;
using u16x4 = __attribute__((ext_vector_type(4))) unsigned short;

__device__ __forceinline__ float bf2f(unsigned short u){
  union { unsigned int i; float f; } v; v.i = ((unsigned int)u) << 16; return v.f;
}
__device__ __forceinline__ unsigned short f2bf(float f){
  union { float f; unsigned int i; } v; v.f = f;
  return (unsigned short)((v.i + 0x7FFFu + ((v.i >> 16) & 1u)) >> 16);
}

#define GLDS16(g, l) __builtin_amdgcn_global_load_lds( \
    (const __attribute__((address_space(1))) unsigned int*)(g), \
    (__attribute__((address_space(3))) unsigned int*)(l), 16, 0, 0)

// ---------------- prep: convert all small operands to bf16 ----------------
__global__ void k_prep(const float* __restrict__ Wd, const float* __restrict__ Wu,
                       const float* __restrict__ Wt, const float* __restrict__ Wf,
                       const float* __restrict__ Ap, const float* __restrict__ Bp,
                       const int* __restrict__ layerp,
                       unsigned short* __restrict__ Wdb, unsigned short* __restrict__ Wub,
                       unsigned short* __restrict__ Wtb, unsigned short* __restrict__ WB,
                       unsigned short* __restrict__ Ab, unsigned short* __restrict__ Blb){
  int idx = blockIdx.x * 256 + threadIdx.x;
  switch (blockIdx.y){
    case 0: if (idx < 24576)  Wdb[idx] = f2bf(Wd[idx]); break;
    case 1: if (idx < 73728)  Wub[idx] = f2bf(Wu[idx]); break;
    case 2: if (idx < 589824) Wtb[idx] = f2bf(Wt[idx]); break;
    case 3: if (idx < 688128){
      int n = idx / 896, c = idx - n * 896;
      WB[idx] = (c < 768) ? f2bf(Wf[n * 768 + c]) : (unsigned short)0;
    } break;
    case 4: if (idx < 28672){
      int r = idx >> 8;
      Ab[idx] = (r < 100) ? f2bf(Ap[idx]) : (unsigned short)0;
    } break;
    case 5: if (idx < 65536) Blb[idx] = f2bf(Bp[(long)(*layerp) * 65536 + idx]); break;
  }
}

// ---------------- generic 1-wave MFMA mini-GEMM: out = epi(A @ B^T + bias) ----------------
template<int EPI>
__global__ __launch_bounds__(64) void k_mm(const unsigned short* __restrict__ A, int lda,
    const unsigned short* __restrict__ B, int ldb, int K,
    const float* __restrict__ bias, unsigned short* __restrict__ out, int ldo){
  int l = threadIdx.x, l15 = l & 15, lhi = l >> 4;
  int m0 = blockIdx.x * 16, n0 = blockIdx.y * 16;
  f32x4 acc = (f32x4)0.0f;
  #pragma unroll 4
  for (int k0 = 0; k0 < K; k0 += 32){
    s16x8 a = *(const s16x8*)(A + (long)(m0 + l15) * lda + k0 + lhi * 8);
    s16x8 b = *(const s16x8*)(B + (long)(n0 + l15) * ldb + k0 + lhi * 8);
    acc = __builtin_amdgcn_mfma_f32_16x16x32_bf16(a, b, acc, 0, 0, 0);
  }
  int col = n0 + l15;
  float bv = bias ? bias[col] : 0.0f;
  #pragma unroll
  for (int r = 0; r < 4; r++){
    int row = m0 + lhi * 4 + r;
    float v = acc[r] + bv;
    if (EPI == 0){
      v = 0.5f * v * (1.0f + erff(v * 0.70710678118654752f));
      out[(long)row * ldo + col] = f2bf(v);
    } else if (EPI == 1){
      out[(long)col * ldo + row] = f2bf(v);
    } else if (EPI == 2){
      out[(long)row * ldo + col] = f2bf(v);
    } else {
      out[(long)col * 896 + 768 + row] = (row < 100) ? f2bf(v) : (unsigned short)0;
    }
  }
}

// ---------------- fused cvt + logits + softmax, LDS-staged GEMM form ----------------
__global__ __launch_bounds__(256, 4) void k_attn(const float* __restrict__ xf,
    const unsigned short* __restrict__ tokensb, unsigned short* __restrict__ xb,
    unsigned short* __restrict__ Pbuf){
  __shared__ __align__(16) char smem[40960];
  unsigned short* Xs = (unsigned short*)smem;            // [32][128] us, swizzled
  unsigned short* Ts = (unsigned short*)(smem + 8192);   // [112][128] us, swizzled
  float* st = (float*)smem;                              // post-loop stash overlay

  int tid = threadIdx.x, w = tid >> 6, l = tid & 63;
  int l15 = l & 15, lhi = l >> 4;
  int rg = w >> 1, kh = w & 1;
  long R0 = (long)blockIdx.x * 32;

  f32x4 acc[7];
  #pragma unroll
  for (int nf = 0; nf < 7; nf++) acc[nf] = (f32x4)0.0f;

  int xrow = tid >> 5;           // 0..7 (8 rows per round)
  int xcol = (tid & 31) * 4;     // f32 col within 128-chunk (coalesced)

  for (int it = 0; it < 6; it++){
    #pragma unroll
    for (int i = 0; i < 7; i++){
      int g = (w * 7 + i) * 4 + (l >> 4);          // token row 0..111
      const unsigned short* src = tokensb + (long)g * 768 + it * 128
                                + (((l & 15) * 8) ^ ((g & 7) << 3));
      GLDS16(src, Ts + (w * 7 + i) * 512);
    }
    #pragma unroll
    for (int rnd = 0; rnd < 4; rnd++){
      int row = rnd * 8 + xrow;
      f32x4 v = *(const f32x4*)(xf + (R0 + row) * 768 + it * 128 + xcol);
      u16x4 c;
      #pragma unroll
      for (int j = 0; j < 4; j++) c[j] = f2bf(v[j]);
      *(u16x4*)(xb + (R0 + row) * 768 + it * 128 + xcol) = c;
      *(u16x4*)(Xs + row * 128 + (xcol ^ ((row & 7) << 3))) = c;
    }
    __syncthreads();
    int ar = rg * 16 + l15;
    #pragma unroll
    for (int kk = 0; kk < 2; kk++){
      int coff = kh * 64 + kk * 32 + lhi * 8;
      s16x8 a = *(const s16x8*)(Xs + ar * 128 + (coff ^ ((ar & 7) << 3)));
      #pragma unroll
      for (int nf = 0; nf < 7; nf++){
        int br = nf * 16 + l15;
        s16x8 b = *(const s16x8*)(Ts + br * 128 + (coff ^ ((br & 7) << 3)));
        acc[nf] = __builtin_amdgcn_mfma_f32_16x16x32_bf16(a, b, acc[nf], 0, 0, 0);
      }
    }
    __syncthreads();
  }

  if (kh == 1){
    int widx = rg * 64 + l;
    #pragma unroll
    for (int nf = 0; nf < 7; nf++)
      #pragma unroll
      for (int r = 0; r < 4; r++)
        st[widx * 29 + nf * 4 + r] = acc[nf][r];
  }
  __syncthreads();
  if (kh == 0){
    const float sc = 0.03608439182435161f; // 768^-0.5
    int widx = rg * 64 + l;
    float lg[4][7];
    #pragma unroll
    for (int nf = 0; nf < 7; nf++)
      #pragma unroll
      for (int r = 0; r < 4; r++)
        lg[r][nf] = (acc[nf][r] + st[widx * 29 + nf * 4 + r]) * sc;
    #pragma unroll
    for (int r = 0; r < 4; r++){
      float mx = -1e30f;
      #pragma unroll
      for (int nf = 0; nf < 7; nf++){
        int col = nf * 16 + l15;
        if (col < 100 && lg[r][nf] > mx) mx = lg[r][nf];
      }
      mx = fmaxf(mx, __shfl_xor(mx, 1));
      mx = fmaxf(mx, __shfl_xor(mx, 2));
      mx = fmaxf(mx, __shfl_xor(mx, 4));
      mx = fmaxf(mx, __shfl_xor(mx, 8));
      float p[7], sm = 0.f;
      #pragma unroll
      for (int nf = 0; nf < 7; nf++){
        int col = nf * 16 + l15;
        float v = (col < 100) ? __expf(lg[r][nf] - mx) : 0.f;
        p[nf] = v; sm += v;
      }
      sm += __shfl_xor(sm, 1);
      sm += __shfl_xor(sm, 2);
      sm += __shfl_xor(sm, 4);
      sm += __shfl_xor(sm, 8);
      float inv = 1.f / sm;
      long grow = R0 + rg * 16 + lhi * 4 + r;
      #pragma unroll
      for (int nf = 0; nf < 7; nf++)
        Pbuf[grow * 128 + nf * 16 + l15] = f2bf(p[nf] * inv);
      Pbuf[grow * 128 + 112 + l15] = 0;
    }
  }
}

// ---------------- big GEMM: out = feats + scale*([xb|P] @ WB^T + bf) ----------------
// BM=256 BN=192 BK=64, grid 512 = 2 exact CU rounds. 8 waves (2M x 4N), wave tile
// 128x48. A tribuf (2-tile-ahead prefetch > HBM latency), B dbuf (L2-resident WB).
// Uniform FIFO: issue B(t+1) @ph0, A(t+2) @ph2; one vmcnt(7)/tile drains {A(t),B(t)}.
__global__ __launch_bounds__(512, 2) void k_gemm(const unsigned short* __restrict__ xb,
    const unsigned short* __restrict__ Pbuf, const unsigned short* __restrict__ WB,
    const float* __restrict__ bfv, const float* __restrict__ scalep,
    float* __restrict__ outf){
  extern __shared__ __align__(16) unsigned short lds[];  // A: 3x16384 us; B: 2x12288 us
  unsigned short* ldsB = lds + 49152;
  int bid = blockIdx.x;                 // 512 = 8 XCD * 64
  int sid = (bid & 7) * 64 + (bid >> 3);
  int mt = sid >> 2, nt = sid & 3;
  long brow = (long)mt * 256;
  int bcol = nt * 192;
  int tid = threadIdx.x, w = tid >> 6, l = tid & 63;
  int l15 = l & 15, lhi = l >> 4;
  int wm = w >> 2, wn = w & 3;          // wave tile: rows wm*128.., cols wn*48..
  int lrow = l >> 3;
  int lsw  = ((l & 7) ^ lrow) * 8;      // pre-swizzled source col (T2 both-sides rule)

  f32x4 acc[8][3];
  #pragma unroll
  for (int m = 0; m < 8; m++)
    #pragma unroll
    for (int n = 0; n < 3; n++) acc[m][n] = (f32x4)0.0f;

  // A-tile: 256x64, 4 issues; each issue: 8 waves x 8 rows. T>=12 reads Pbuf.
  #define STAGE_A(BUF, T) { \
    _Pragma("unroll") \
    for (int ii = 0; ii < 4; ii++){ \
      int r = ii * 64 + w * 8 + lrow; \
      const unsigned short* ga = ((T) < 12) \
        ? xb   + (brow + r) * 768 + (T) * 64 + lsw \
        : Pbuf + (brow + r) * 128 + ((T) - 12) * 64 + lsw; \
      GLDS16(ga, lds + (BUF) * 16384 + (ii * 64 + w * 8) * 64); \
    } }
  // B-tile: 192x64, 3 issues
  #define STAGE_B(BUF, T) { \
    _Pragma("unroll") \
    for (int ii = 0; ii < 3; ii++){ \
      int r = ii * 64 + w * 8 + lrow; \
      const unsigned short* gb = WB + (long)(bcol + r) * 896 + (T) * 64 + lsw; \
      GLDS16(gb, ldsB + (BUF) * 12288 + (ii * 64 + w * 8) * 64); \
    } }

  #define LDA(dst, M, KS) { \
    int ar = wm * 128 + (M) * 16 + l15; \
    int xo = ((KS) * 64 + lhi * 16) ^ ((ar & 7) << 4); \
    dst = *(const s16x8*)(Abuf + ar * 64 + (xo >> 1)); }
  #define LDB(dst, N, KS) { \
    int br = wn * 48 + (N) * 16 + l15; \
    int xo = ((KS) * 64 + lhi * 16) ^ ((br & 7) << 4); \
    dst = *(const s16x8*)(Bbuf + br * 64 + (xo >> 1)); }

  // prologue in FIFO order: A(0), B(0), A(1)
  STAGE_A(0, 0);
  STAGE_B(0, 0);
  STAGE_A(1, 1);

  for (int t = 0; t < 14; t++){
    const unsigned short* Abuf = lds + (t % 3) * 16384;
    const unsigned short* Bbuf = ldsB + (t & 1) * 12288;
    s16x8 af[4], bk[3];
    // ---- phase 0: issue B(t+1); wait {A(t),B(t)}; (qm=0, ks=0) ----
    { int Tb = (t + 1 < 14) ? t + 1 : 13;  // clamped dup keeps FIFO uniform (L2 hit)
      STAGE_B((t + 1) & 1, Tb); }
    asm volatile("s_waitcnt vmcnt(7)" ::: "memory");
    __builtin_amdgcn_s_barrier();
    #pragma unroll
    for (int j = 0; j < 3; j++) LDB(bk[j], j, 0);
    #pragma unroll
    for (int j = 0; j < 4; j++) LDA(af[j], j, 0);
    __builtin_amdgcn_s_setprio(1);
    #pragma unroll
    for (int m = 0; m < 4; m++)
      #pragma unroll
      for (int n = 0; n < 3; n++)
        acc[m][n] = __builtin_amdgcn_mfma_f32_16x16x32_bf16(af[m], bk[n], acc[m][n], 0, 0, 0);
    __builtin_amdgcn_s_setprio(0);
    __builtin_amdgcn_s_barrier();
    // ---- phase 1: (qm=1, ks=0) ----
    #pragma unroll
    for (int j = 0; j < 4; j++) LDA(af[j], 4 + j, 0);
    __builtin_amdgcn_s_setprio(1);
    #pragma unroll
    for (int m = 0; m < 4; m++)
      #pragma unroll
      for (int n = 0; n < 3; n++)
        acc[4 + m][n] = __builtin_amdgcn_mfma_f32_16x16x32_bf16(af[m], bk[n], acc[4 + m][n], 0, 0, 0);
    __builtin_amdgcn_s_setprio(0);
    __builtin_amdgcn_s_barrier();
    // ---- phase 2: issue A(t+2); (qm=0, ks=1) ----
    { int Ta = (t + 2 < 14) ? t + 2 : 13;  // clamped dup (Pbuf = L2 hit)
      int ab = (t + 2) % 3;
      STAGE_A(ab, Ta); }
    #pragma unroll
    for (int j = 0; j < 3; j++) LDB(bk[j], j, 1);
    #pragma unroll
    for (int j = 0; j < 4; j++) LDA(af[j], j, 1);
    __builtin_amdgcn_s_setprio(1);
    #pragma unroll
    for (int m = 0; m < 4; m++)
      #pragma unroll
      for (int n = 0; n < 3; n++)
        acc[m][n] = __builtin_amdgcn_mfma_f32_16x16x32_bf16(af[m], bk[n], acc[m][n], 0, 0, 0);
    __builtin_amdgcn_s_setprio(0);
    __builtin_amdgcn_s_barrier();
    // ---- phase 3: (qm=1, ks=1) ----
    #pragma unroll
    for (int j = 0; j < 4; j++) LDA(af[j], 4 + j, 1);
    __builtin_amdgcn_s_setprio(1);
    #pragma unroll
    for (int m = 0; m < 4; m++)
      #pragma unroll
      for (int n = 0; n < 3; n++)
        acc[4 + m][n] = __builtin_amdgcn_mfma_f32_16x16x32_bf16(af[m], bk[n], acc[4 + m][n], 0, 0, 0);
    __builtin_amdgcn_s_setprio(0);
    __builtin_amdgcn_s_barrier();
  }
  #undef STAGE_A
  #undef STAGE_B
  #undef LDA
  #undef LDB

  // drain dup prefetches before overwriting LDS
  asm volatile("s_waitcnt vmcnt(0)" ::: "memory");
  __syncthreads();

  // ---- coalesced epilogue: acc -> LDS (f32, stride 196) -> 256B-coalesced stores ----
  float* stf = (float*)lds;      // 128 x 196 f32 = 100,352 B (dyn LDS = 147,456)
  float scale = *scalep;
  #pragma unroll
  for (int c = 0; c < 2; c++){
    if (wm == c){
      #pragma unroll
      for (int m = 0; m < 8; m++)
        #pragma unroll
        for (int n = 0; n < 3; n++)
          #pragma unroll
          for (int r = 0; r < 4; r++){
            int row = m * 16 + lhi * 4 + r;
            stf[row * 196 + wn * 48 + n * 16 + l15] = acc[m][n][r];
          }
    }
    __syncthreads();
    #pragma unroll
    for (int rp = 0; rp < 4; rp++){
      int row = rp * 32 + (tid >> 4);
      long grow = brow + c * 128 + row;
      #pragma unroll
      for (int cb = 0; cb < 3; cb++){
        int col = cb * 64 + (tid & 15) * 4;
        f32x4 v = *(const f32x4*)(stf + row * 196 + col);
        int gcol = bcol + col;
        f32x4 bias = *(const f32x4*)(bfv + gcol);
        u16x4 fb = *(const u16x4*)(xb + grow * 768 + gcol);
        f32x4 o;
        #pragma unroll
        for (int j = 0; j < 4; j++) o[j] = bf2f(fb[j]) + scale * (v[j] + bias[j]);
        *(f32x4*)(outf + grow * 768 + gcol) = o;
      }
    }
    __syncthreads();
  }
}

extern "C" void kernel_launch(void* const* d_in, const int* in_sizes, int n_in,
                              void* d_out, int out_size, void* d_ws, size_t ws_size,
                              hipStream_t stream) {
  const float* x   = (const float*)d_in[0];
  const float* Wd  = (const float*)d_in[1];
  const float* bd  = (const float*)d_in[2];
  const float* Wu  = (const float*)d_in[3];
  const float* bu  = (const float*)d_in[4];
  const float* Wt  = (const float*)d_in[5];
  const float* bt  = (const float*)d_in[6];
  const float* Wf  = (const float*)d_in[7];
  const float* bfv = (const float*)d_in[8];
  const float* Ap  = (const float*)d_in[9];
  const float* Bp  = (const float*)d_in[10];
  const float* scalep = (const float*)d_in[11];
  const int* layerp   = (const int*)d_in[12];
  float* out = (float*)d_out;

  char* ws = (char*)d_ws;
  unsigned short* xb      = (unsigned short*)(ws);              // 50,331,648
  unsigned short* Pbuf    = (unsigned short*)(ws + 50331648);   //  8,388,608
  unsigned short* WB      = (unsigned short*)(ws + 58720256);   //  1,376,256 (768 x 896)
  unsigned short* Wtb     = (unsigned short*)(ws + 60096512);   //  1,179,648 (768 x 768)
  unsigned short* tokensb = (unsigned short*)(ws + 61276160);   //    172,032 (112 x 768)
  unsigned short* t2fb    = (unsigned short*)(ws + 61448192);   //    172,032 (112 x 768)
  unsigned short* Ab      = (unsigned short*)(ws + 61620224);   //     57,344 (112 x 256)
  unsigned short* Blb     = (unsigned short*)(ws + 61677568);   //    131,072 (256 x 256)
  unsigned short* Wdb     = (unsigned short*)(ws + 61808640);   //     49,152 ( 96 x 256)
  unsigned short* Wub     = (unsigned short*)(ws + 61857792);   //    147,456 (768 x  96)
  unsigned short* hb      = (unsigned short*)(ws + 62005248);   //     49,152 (256 x  96)
  unsigned short* Bfmt    = (unsigned short*)(ws + 62054400);   //    393,216 (768 x 256, Bf^T)

  const float* xf = x + 32 * 768;   // feats (skip cls rows)
  float* outf = out + 32 * 768;

  static int lds_attr_set = 0;
  if (!lds_attr_set){
    hipFuncSetAttribute((const void*)k_gemm, hipFuncAttributeMaxDynamicSharedMemorySize, 147456);
    lds_attr_set = 1;
  }

  // cls passthrough
  hipMemcpyAsync(d_out, d_in[0], 32 * 768 * sizeof(float), hipMemcpyDeviceToDevice, stream);

  k_prep<<<dim3(2688, 6), 256, 0, stream>>>(Wd, Wu, Wt, Wf, Ap, Bp, layerp,
                                            Wdb, Wub, Wtb, WB, Ab, Blb);
  k_mm<0><<<dim3(16, 6),  64, 0, stream>>>(Blb, 256, Wdb, 256, 256, bd, hb, 96);
  k_mm<1><<<dim3(16, 48), 64, 0, stream>>>(hb, 96, Wub, 96, 96, bu, Bfmt, 256);
  k_mm<2><<<dim3(7, 48),  64, 0, stream>>>(Ab, 256, Bfmt, 256, 256, nullptr, tokensb, 768);
  k_mm<2><<<dim3(7, 48),  64, 0, stream>>>(tokensb, 768, Wtb, 768, 768, bt, t2fb, 768);
  k_mm<3><<<dim3(7, 48),  64, 0, stream>>>(t2fb, 768, WB, 896, 768, nullptr, WB, 0);

  k_attn<<<1024, 256, 0, stream>>>(xf, tokensb, xb, Pbuf);
  k_gemm<<<512, 512, 147456, stream>>>(xb, Pbuf, WB, bfv, scalep, outf);
}